// Round 1
// baseline (242.025 us; speedup 1.0000x reference)
//
#include <hip/hip_runtime.h>
#include <hip/hip_bf16.h>

#define B_ 4
#define S_ 2048
#define HD 1024
#define NH 8
#define DK 128
#define WA 67
#define WPAD 80      // cD^T rows: 0..66 data, 67 = ones (l-column), 68..79 zero

typedef __attribute__((ext_vector_type(8))) short short8;
typedef __attribute__((ext_vector_type(4))) short short4v;
typedef __attribute__((ext_vector_type(4))) float floatx4;

// hardware exp2: one v_exp_f32 (avoid __exp2f - glibc macro collision)
__device__ __forceinline__ float hexp2(float x) { return __builtin_amdgcn_exp2f(x); }

__device__ __forceinline__ short f2bf(float f) {
    union { float f; unsigned u; } c; c.f = f;
    unsigned u = c.u;
    u += 0x7FFF + ((u >> 16) & 1);          // RTNE
    return (short)(u >> 16);
}
__device__ __forceinline__ float bf2f(short s) {
    union { unsigned u; float f; } c; c.u = ((unsigned)(unsigned short)s) << 16;
    return c.f;
}
__device__ __forceinline__ short f2bf_trunc(float f) {
    union { float f; unsigned u; } c; c.f = f;
    return (short)(c.u >> 16);
}

// async 16B global->LDS DMA; LDS dest = wave-uniform base, lane i lands at
// base + i*16. Per-lane global address is free to choose -> XOR swizzle there.
__device__ __forceinline__ void glds16(void* lds, const void* g) {
    __builtin_amdgcn_global_load_lds(
        (const __attribute__((address_space(1))) unsigned*)g,
        (__attribute__((address_space(3))) unsigned*)lds, 16, 0, 0);
}

// db4 filters, pre-reversed for correlation: F[j] = DEC_*[7-j]
__device__ __constant__ float FLO[8] = {
    0.23037781330885523f,  0.7148465705525415f,  0.6308807679295904f,
   -0.02798376941698385f, -0.18703481171888114f, 0.030841381835986965f,
    0.032883011666982945f, -0.010597401784997278f };
__device__ __constant__ float FHI[8] = {
   -0.010597401784997278f, -0.032883011666982945f, 0.030841381835986965f,
    0.18703481171888114f,  -0.02798376941698385f, -0.6308807679295904f,
    0.7148465705525415f,   -0.23037781330885523f };

// ------- fp32 -> bf16 bulk convert, all four inputs in ONE launch ----------
__global__ __launch_bounds__(256) void cvt_all(
    const float* __restrict__ x,  const float* __restrict__ wq,
    const float* __restrict__ wk, const float* __restrict__ wv,
    short* __restrict__ xb, short* __restrict__ wb)
{
    const size_t w_elems = (size_t)HD * HD;
    int blk = blockIdx.x;
    const float* src; short* dst; int lb;
    if (blk < 4096)      { src = x;  dst = xb;               lb = blk; }
    else if (blk < 4608) { src = wq; dst = wb;               lb = blk - 4096; }
    else if (blk < 5120) { src = wk; dst = wb + w_elems;     lb = blk - 4608; }
    else                 { src = wv; dst = wb + 2 * w_elems; lb = blk - 5120; }
    int i = lb * 256 + threadIdx.x;
    const float4* s = (const float4*)src + (size_t)i * 2;
    float4 f0 = s[0], f1 = s[1];
    short8 o;
    o[0] = f2bf(f0.x); o[1] = f2bf(f0.y); o[2] = f2bf(f0.z); o[3] = f2bf(f0.w);
    o[4] = f2bf(f1.x); o[5] = f2bf(f1.y); o[6] = f2bf(f1.z); o[7] = f2bf(f1.w);
    *((short8*)dst + i) = o;
}

// ------- QKV projection + fused DWT: 256x256xBK64, 8-phase counted-vmcnt ----
// One fused GEMM over N=3072 (Wq|Wk|Wv). 8 waves (2M x 4N), per-wave output
// 128x64 split as 2x2 interleaved quadrants so each phase reads exactly one
// A-half + one B-half. Per K-tile: 4 phases, each = {12 ds_read_b128, stage
// one future half-tile via global_load_lds, barrier, setprio(1)+16 MFMA,
// counted vmcnt(8), barrier}. vmcnt never drains to 0 in the loop: 4-5
// half-tiles (8-10 loads) stay in flight across barriers. Half-tile stream
// per tile t: P1->A1[t+1], P2->B1[t+1], P3->B0[t+2], P4->A0[t+2]; every
// slot's overwrite is barrier-separated from its last reader, and every read
// is preceded (per wave) by a vmcnt covering its own copy of that half +
// a barrier (cross-wave visibility). Tail tiles stage wrapped (dummy) data,
// drained by the epilogue __syncthreads before LDS reuse.
// z==2 (V): epilogue restages the 256x256 V tile (2 heads) into LDS in two
// 128-row passes (stride 258 shorts, gcd(129,32)=1 -> conflict-free) and
// computes the db4 DWT in-block: cA -> out2, cD^T (+ones row 67) -> cdt.
__global__ __launch_bounds__(512, 2) void qkv_gemm(
    const short* __restrict__ xb, const short* __restrict__ Wb,
    short* __restrict__ Qb, short* __restrict__ Kb,
    float* __restrict__ outA, short* __restrict__ cdt)
{
    __shared__ __align__(16) short lds[2][2][2][8192]; // [buf][A/B][half][128*64] = 128KB
    const int tid  = threadIdx.x;
    const int wid  = tid >> 6;
    const int lane = tid & 63;
    const int l15  = lane & 15;
    const int quad = lane >> 4;
    const int rxor = l15 & 7;
    const int wm   = wid >> 2;            // 0..1  (m-position of wave)
    const int wq   = wid & 3;             // 0..3  (n-position of wave)
    const int m0 = blockIdx.x * 256;
    const int by = blockIdx.y;            // 0..11
    const int z  = by >> 2;               // 0=Q 1=K 2=V
    const int nz0 = (by & 3) * 256;       // n-offset within the z-th weight
    const short* W = Wb + (size_t)z * HD * HD;
    // q scale folded with log2(e) so attention softmax can use exp2
    const float scale = (z == 0) ? 0.12751743786072596f : 1.0f;

    floatx4 acc[2][2][4][2] = {};         // [mh][nh][mt][nt]

    // stage one 128x64 half-tile (16KB): 2 glds16/wave, source pre-XOR-swizzled
    auto stA = [&](int bf, int hf, int t) {
        const short* g = xb + (size_t)(m0 + hf * 128) * HD + t * 64;
        short* slot = &lds[bf][0][hf][0];
        #pragma unroll
        for (int i = 0; i < 2; ++i) {
            int ti = wid * 2 + i;
            int r  = ti * 8 + (lane >> 3);
            int ch = (lane & 7) ^ (lane >> 3);      // r&7 == lane>>3
            glds16(slot + ti * 512, g + (size_t)r * HD + ch * 8);
        }
    };
    auto stB = [&](int bf, int hf, int t) {
        const short* g = W + (size_t)(nz0 + hf * 128) * HD + t * 64;
        short* slot = &lds[bf][1][hf][0];
        #pragma unroll
        for (int i = 0; i < 2; ++i) {
            int ti = wid * 2 + i;
            int r  = ti * 8 + (lane >> 3);
            int ch = (lane & 7) ^ (lane >> 3);
            glds16(slot + ti * 512, g + (size_t)r * HD + ch * 8);
        }
    };

#define VM8 asm volatile("s_waitcnt vmcnt(8)" ::: "memory")
#define BARRIER do { asm volatile("" ::: "memory"); \
                     __builtin_amdgcn_s_barrier(); \
                     asm volatile("" ::: "memory"); } while (0)
#define PHASE(MH, NH, STG) do { \
    short8 afr[4][2], bfr[2][2]; \
    const short* Ab = &lds[cur][0][MH][0]; \
    const short* Bb = &lds[cur][1][NH][0]; \
    _Pragma("unroll") \
    for (int mt = 0; mt < 4; ++mt) { \
        const int rr = (wm * 64 + mt * 16 + l15) * 64; \
        afr[mt][0] = *(const short8*)&Ab[rr + ((quad ^ rxor) * 8)]; \
        afr[mt][1] = *(const short8*)&Ab[rr + (((4 + quad) ^ rxor) * 8)]; \
    } \
    _Pragma("unroll") \
    for (int nt = 0; nt < 2; ++nt) { \
        const int rr = (wq * 32 + nt * 16 + l15) * 64; \
        bfr[nt][0] = *(const short8*)&Bb[rr + ((quad ^ rxor) * 8)]; \
        bfr[nt][1] = *(const short8*)&Bb[rr + (((4 + quad) ^ rxor) * 8)]; \
    } \
    STG; \
    BARRIER; \
    __builtin_amdgcn_s_setprio(1); \
    _Pragma("unroll") \
    for (int ks = 0; ks < 2; ++ks) \
        _Pragma("unroll") \
        for (int mt = 0; mt < 4; ++mt) \
            _Pragma("unroll") \
            for (int nt = 0; nt < 2; ++nt) \
                acc[MH][NH][mt][nt] = __builtin_amdgcn_mfma_f32_16x16x32_bf16( \
                    afr[mt][ks], bfr[nt][ks], acc[MH][NH][mt][nt], 0, 0, 0); \
    __builtin_amdgcn_s_setprio(0); \
} while (0)

    // prologue: 6 half-tiles issued; vmcnt(8) completes tile-0's A0/B0
    stB(0, 0, 0); stA(0, 0, 0); stA(0, 1, 0); stB(0, 1, 0);
    stB(1, 0, 1); stA(1, 0, 1);
    VM8; BARRIER;

    #pragma unroll 2
    for (int t = 0; t < 16; ++t) {
        const int cur = t & 1, nxt = cur ^ 1;
        const int ta = (t + 1) & 15, tb = (t + 2) & 15;   // wrap = dummy tail stage
        PHASE(0, 0, stA(nxt, 1, ta)); VM8; BARRIER;
        PHASE(1, 0, stB(nxt, 1, ta)); VM8; BARRIER;
        PHASE(0, 1, stB(cur, 0, tb));      BARRIER;
        PHASE(1, 1, stA(cur, 0, tb)); VM8; BARRIER;
    }
    __syncthreads();   // drains vmcnt(0): dummy stagings land before LDS reuse

    // C layout per fragment: col = l15 (N), row = quad*4+reg (M).
    if (z != 2) {
        short* Yb = (z == 0) ? Qb : Kb;
        #pragma unroll
        for (int mh = 0; mh < 2; ++mh)
            #pragma unroll
            for (int nh = 0; nh < 2; ++nh)
                #pragma unroll
                for (int mt = 0; mt < 4; ++mt)
                    #pragma unroll
                    for (int nt = 0; nt < 2; ++nt)
                        #pragma unroll
                        for (int reg = 0; reg < 4; ++reg) {
                            int rg = m0 + mh * 128 + wm * 64 + mt * 16 + quad * 4 + reg;
                            int cg = nz0 + nh * 128 + wq * 32 + nt * 16 + l15;
                            int b = rg >> 11, s = rg & 2047;
                            int h = cg >> 7,  d = cg & 127;
                            Yb[((size_t)(b * NH + h) * S_ + s) * DK + d] =
                                f2bf(acc[mh][nh][mt][nt][reg] * scale);
                        }
        return;
    }
    // ---- z==2: V tile (2 heads) -> LDS in two 128-row passes, fused DWT ----
    short* Cs = &lds[0][0][0][0];            // 128 x 258 shorts = 66KB
    const int rl    = tid & 127;             // local V row (s) within pass
    const int hl    = (tid >> 7) & 1;        // which of the 2 heads
    const int chunk = tid >> 8;              // t-half 0/1
    #pragma unroll
    for (int mh = 0; mh < 2; ++mh) {
        __syncthreads();                     // prior pass done reading Cs
        #pragma unroll
        for (int nh = 0; nh < 2; ++nh)
            #pragma unroll
            for (int mt = 0; mt < 4; ++mt)
                #pragma unroll
                for (int nt = 0; nt < 2; ++nt)
                    #pragma unroll
                    for (int reg = 0; reg < 4; ++reg) {
                        int r = wm * 64 + mt * 16 + quad * 4 + reg;
                        int c = nh * 128 + wq * 32 + nt * 16 + l15;
                        Cs[r * 258 + c] = f2bf(acc[mh][nh][mt][nt][reg]);
                    }
        __syncthreads();
        const int rg = m0 + mh * 128 + rl;
        const int b = rg >> 11, s = rg & 2047;
        const int hg = (by & 3) * 2 + hl;
        const int bh = b * NH + hg;
        const short* vr = Cs + rl * 258 + hl * 128;
        auto getv = [&](int i) -> float {
            int k = (i < 6) ? (5 - i) : (i < 134) ? (i - 6) : (261 - i);
            return bf2f(vr[k]);
        };
        const int t0  = chunk * 34;
        const int t1c = (chunk == 0) ? 34 : WA;
        float win[8];
        #pragma unroll
        for (int j = 0; j < 8; ++j) win[j] = getv(2 * t0 + j);
        float* oA = outA + ((size_t)bh * S_ + s) * WA;
        for (int t = t0; t < t1c; ++t) {
            float lo = 0.f, hi = 0.f;
            #pragma unroll
            for (int j = 0; j < 8; ++j) { lo += win[j] * FLO[j]; hi += win[j] * FHI[j]; }
            oA[t] = lo;                                          // contiguous per thread
            cdt[((size_t)bh * WPAD + t) * S_ + s] = f2bf(hi);    // lane-coalesced over s
            #pragma unroll
            for (int j = 0; j < 6; ++j) win[j] = win[j + 2];
            if (t + 1 < t1c) { win[6] = getv(2 * t + 8); win[7] = getv(2 * t + 9); }
        }
        if (chunk == 1) {
            #pragma unroll
            for (int w = WA; w < WPAD; ++w)
                cdt[((size_t)bh * WPAD + w) * S_ + s] =
                    (w == 67) ? (short)0x3F80 : (short)0;   // ones row 67 (l), else 0
        }
    }
#undef PHASE
#undef BARRIER
#undef VM8
}

// ---------------- flash attention: out1 = softmax(QK^T) @ cD ----------------
// 128 q-rows/block (32/wave), grid 16x32=512. Single-buffer staging (proven
// vs dbuf/split-K). S^T trick (A=K, B=Q) packs P as b64 into wave-private
// XOR-swizzled LDS. Unnormalized softmax (|s| < ~15, exp2 domain); the l-sum
// comes FREE from the PV MFMA via the ones-row at w=67 (col 67 of j=4 tile).
__global__ __launch_bounds__(256, 2) void attn_kernel(
    const short* __restrict__ Qb, const short* __restrict__ Kb,
    const short* __restrict__ cdt, float* __restrict__ out1)
{
    __shared__ __align__(16) short Ks[64 * 128];      // 16KB, 16 chunks/row
    __shared__ __align__(16) short Ds[WPAD * 64];     // 10KB, 8 chunks/row
    __shared__ __align__(16) short Pt[8 * 1024];      // 16KB, wave-private P
    const int tid  = threadIdx.x;
    const int wv   = tid >> 6;
    const int lane = tid & 63;
    const int l15  = lane & 15;
    const int quad = lane >> 4;
    const int qt = blockIdx.x;           // 0..15 (128 q-rows each)
    const int bh = blockIdx.y;           // 0..31
    const int b = bh >> 3, h = bh & 7;
    const int rxor = l15 & 7;

    // Q fragments from global, once. Lane layout = row l15, k = quad*8+j
    // (identical for A- and B-operands, so they serve as B in S^T = K Q^T).
    short8 aq[2][4];
    #pragma unroll
    for (int n = 0; n < 2; ++n) {
        const short* qrow =
            Qb + ((size_t)bh * S_ + qt * 128 + wv * 32 + n * 16 + l15) * DK;
        #pragma unroll
        for (int s4 = 0; s4 < 4; ++s4)
            aq[n][s4] = *(const short8*)(qrow + s4 * 32 + quad * 8);
    }

    floatx4 O[2][5] = {};                // j=4 tile col 67 accumulates l

    const short* kbase = Kb + (size_t)bh * S_ * DK;
    const int krow = lane >> 4;                    // K staging: 4 rows/issue
    const int kch  = (lane & 15);
    const int drow = lane >> 3;                    // D staging: 8 rows/issue
    const int dch  = (lane & 7) ^ (drow & 7);
    short* ptw = Pt + wv * 2048;                   // this wave's P (2 tiles)

    for (int kt = 0; kt < 32; ++kt) {
        __syncthreads();                 // prior iter done reading Ks/Ds
        #pragma unroll
        for (int i = 0; i < 4; ++i) {    // K tile: 64 rows x 256B, 16 issues
            int ti = wv * 4 + i;
            int r  = ti * 4 + krow;
            int ch = kch ^ (r & 7);
            glds16(Ks + ti * 512, kbase + ((size_t)kt * 64 + r) * DK + ch * 8);
        }
        #pragma unroll
        for (int i = 0; i < 3; ++i) {    // D tile: 80 rows x 128B, 10 issues
            int t = wv + i * 4;
            if (t < 10) {
                int r = t * 8 + drow;
                glds16(Ds + t * 512,
                       cdt + ((size_t)bh * WPAD + r) * S_ + kt * 64 + dch * 8);
            }
        }
        __syncthreads();                 // vmcnt drained -> tiles ready

        // S^T = K Q^T : C col=l15=q-row, row=quad*4+reg=key
        floatx4 sc[2][4] = {};
        #pragma unroll
        for (int s4 = 0; s4 < 4; ++s4) {
            short8 kf[4];
            #pragma unroll
            for (int mt = 0; mt < 4; ++mt) {
                int ch = (s4 * 4 + quad) ^ rxor;
                kf[mt] = *(const short8*)&Ks[(mt * 16 + l15) * 128 + ch * 8];
            }
            #pragma unroll
            for (int n = 0; n < 2; ++n)
                #pragma unroll
                for (int mt = 0; mt < 4; ++mt)
                    sc[n][mt] = __builtin_amdgcn_mfma_f32_16x16x32_bf16(
                        kf[mt], aq[n][s4], sc[n][mt], 0, 0, 0);
        }
        // p = 2^s; 4 regs = 4 consecutive keys of q-row n*16+l15 -> b64 pack
        #pragma unroll
        for (int n = 0; n < 2; ++n) {
            #pragma unroll
            for (int mt = 0; mt < 4; ++mt) {
                short4v pk;
                #pragma unroll
                for (int reg = 0; reg < 4; ++reg)
                    pk[reg] = f2bf_trunc(hexp2(sc[n][mt][reg]));
                int ch = (mt * 2 + (quad >> 1)) ^ rxor;
                *(short4v*)&ptw[n * 1024 + l15 * 64 + ch * 8 + (quad & 1) * 4] = pk;
            }
        }
        // O += P @ cD   (col 67 of j=4 accumulates l via the ones row)
        short8 ap[2][2];
        #pragma unroll
        for (int mt = 0; mt < 2; ++mt)
            #pragma unroll
            for (int ks = 0; ks < 2; ++ks) {
                int ch = (ks * 4 + quad) ^ rxor;
                ap[mt][ks] = *(const short8*)&ptw[mt * 1024 + l15 * 64 + ch * 8];
            }
        #pragma unroll
        for (int j = 0; j < 5; ++j) {
            #pragma unroll
            for (int ks = 0; ks < 2; ++ks) {
                int ch = (ks * 4 + quad) ^ rxor;
                short8 bd = *(const short8*)&Ds[(j * 16 + l15) * 64 + ch * 8];
                #pragma unroll
                for (int mt = 0; mt < 2; ++mt)
                    O[mt][j] = __builtin_amdgcn_mfma_f32_16x16x32_bf16(
                        ap[mt][ks], bd, O[mt][j], 0, 0, 0);
            }
        }
    }
    // l(r) sits at element (row r, col 67) = lane (r>>2)*16+3, reg r&3 of j=4.
    float rl[2][4];
    #pragma unroll
    for (int mt = 0; mt < 2; ++mt)
        #pragma unroll
        for (int reg = 0; reg < 4; ++reg)
            rl[mt][reg] = 1.0f / __shfl(O[mt][4][reg], (quad << 4) | 3, 64);
    // epilogue: out1[b][q][h*67+w] = O * (1/l)   (w >= 67 dropped)
    #pragma unroll
    for (int mt = 0; mt < 2; ++mt)
        #pragma unroll
        for (int j = 0; j < 5; ++j) {
            int w = j * 16 + l15;
            if (w < WA) {
                #pragma unroll
                for (int reg = 0; reg < 4; ++reg) {
                    int qrow_g = qt * 128 + wv * 32 + mt * 16 + quad * 4 + reg;
                    out1[((size_t)(b * S_ + qrow_g)) * (NH * WA) + h * WA + w] =
                        O[mt][j][reg] * rl[mt][reg];
                }
            }
        }
}

extern "C" void kernel_launch(void* const* d_in, const int* in_sizes, int n_in,
                              void* d_out, int out_size, void* d_ws, size_t ws_size,
                              hipStream_t stream)
{
    const float* x  = (const float*)d_in[0];
    const float* Wq = (const float*)d_in[1];
    const float* Wk = (const float*)d_in[2];
    const float* Wv = (const float*)d_in[3];
    float* out = (float*)d_out;

    const size_t x_elems   = (size_t)B_ * S_ * HD;           // 8,388,608
    const size_t w_elems   = (size_t)HD * HD;                // 1,048,576
    const size_t qkv_elems = (size_t)B_ * NH * S_ * DK;      // 8,388,608
    short* xb  = (short*)d_ws;
    short* Wb  = xb + x_elems;                               // 3 concatenated
    short* Qb  = Wb + 3 * w_elems;
    short* Kb  = Qb + qkv_elems;
    short* cdt = Kb + qkv_elems;                             // (b,h,w=80,s) bf16
    float* out1 = out;                                       // (B,S,536)
    float* out2 = out + (size_t)B_ * S_ * NH * WA;           // (B,H,S,67)

    cvt_all<<<dim3(5632), 256, 0, stream>>>(x, Wq, Wk, Wv, xb, Wb);
    qkv_gemm<<<dim3(32, 12), 512, 0, stream>>>(xb, Wb, Qb, Kb, out2, cdt);
    attn_kernel<<<dim3(16, 32), 256, 0, stream>>>(Qb, Kb, cdt, out1);
}

// Round 2
// 233.752 us; speedup vs baseline: 1.0354x; 1.0354x over previous
//
#include <hip/hip_runtime.h>
#include <hip/hip_bf16.h>

#define B_ 4
#define S_ 2048
#define HD 1024
#define NH 8
#define DK 128
#define WA 67
#define WPAD 80      // cD^T rows: 0..66 data, 67 = ones (l-column), 68..79 zero

typedef __attribute__((ext_vector_type(8))) short short8;
typedef __attribute__((ext_vector_type(4))) short short4v;
typedef __attribute__((ext_vector_type(4))) float floatx4;

// hardware exp2: one v_exp_f32 (avoid __exp2f - glibc macro collision)
__device__ __forceinline__ float hexp2(float x) { return __builtin_amdgcn_exp2f(x); }

__device__ __forceinline__ short f2bf(float f) {
    union { float f; unsigned u; } c; c.f = f;
    unsigned u = c.u;
    u += 0x7FFF + ((u >> 16) & 1);          // RTNE
    return (short)(u >> 16);
}
__device__ __forceinline__ float bf2f(short s) {
    union { unsigned u; float f; } c; c.u = ((unsigned)(unsigned short)s) << 16;
    return c.f;
}
__device__ __forceinline__ short f2bf_trunc(float f) {
    union { float f; unsigned u; } c; c.f = f;
    return (short)(c.u >> 16);
}

// async 16B global->LDS DMA; LDS dest = wave-uniform base, lane i lands at
// base + i*16. Per-lane global address is free to choose -> XOR swizzle there.
__device__ __forceinline__ void glds16(void* lds, const void* g) {
    __builtin_amdgcn_global_load_lds(
        (const __attribute__((address_space(1))) unsigned*)g,
        (__attribute__((address_space(3))) unsigned*)lds, 16, 0, 0);
}

// db4 filters, pre-reversed for correlation: F[j] = DEC_*[7-j]
__device__ __constant__ float FLO[8] = {
    0.23037781330885523f,  0.7148465705525415f,  0.6308807679295904f,
   -0.02798376941698385f, -0.18703481171888114f, 0.030841381835986965f,
    0.032883011666982945f, -0.010597401784997278f };
__device__ __constant__ float FHI[8] = {
   -0.010597401784997278f, -0.032883011666982945f, 0.030841381835986965f,
    0.18703481171888114f,  -0.02798376941698385f, -0.6308807679295904f,
    0.7148465705525415f,   -0.23037781330885523f };

// ------- fp32 -> bf16 bulk convert, all four inputs in ONE launch ----------
__global__ __launch_bounds__(256) void cvt_all(
    const float* __restrict__ x,  const float* __restrict__ wq,
    const float* __restrict__ wk, const float* __restrict__ wv,
    short* __restrict__ xb, short* __restrict__ wb)
{
    const size_t w_elems = (size_t)HD * HD;
    int blk = blockIdx.x;
    const float* src; short* dst; int lb;
    if (blk < 4096)      { src = x;  dst = xb;               lb = blk; }
    else if (blk < 4608) { src = wq; dst = wb;               lb = blk - 4096; }
    else if (blk < 5120) { src = wk; dst = wb + w_elems;     lb = blk - 4608; }
    else                 { src = wv; dst = wb + 2 * w_elems; lb = blk - 5120; }
    int i = lb * 256 + threadIdx.x;
    const float4* s = (const float4*)src + (size_t)i * 2;
    float4 f0 = s[0], f1 = s[1];
    short8 o;
    o[0] = f2bf(f0.x); o[1] = f2bf(f0.y); o[2] = f2bf(f0.z); o[3] = f2bf(f0.w);
    o[4] = f2bf(f1.x); o[5] = f2bf(f1.y); o[6] = f2bf(f1.z); o[7] = f2bf(f1.w);
    *((short8*)dst + i) = o;
}

// ------- QKV projection + fused DWT: 256x128xBK64, triple-buffered ---------
// One fused GEMM over N=3072 (Wq|Wk|Wv). Tile 256(M)x128(N), BK=64, 8 waves
// (4M x 2N, wave tile 64x64). Grid 32x24 = 768 blocks = EXACTLY 3 rounds of
// 256 CUs at 1 block/CU (144KB LDS) -- fixes round-1's 1.5-round imbalance.
// TRIPLE-buffered staging gives a full K-tile of vmcnt slack: during tile t's
// 2 phases we stage tile t+2 into buf[(t+2)%3] (freed by tile t-1's last
// barrier). ONE counted vmcnt(6) per tile, at phase 1 before the pre-MFMA
// barrier: it leaves exactly this tile's 6 loads in flight and completes all
// older ones -- i.e. tile t+1's loads, staged a full tile (~600cy) earlier.
// vmcnt never drains to 0 in the main loop (only the t==14 tail). Each phase:
// {8 ds_read_b128, stage, [vmcnt], barrier, setprio(1)+16 MFMA, setprio(0),
// barrier} -- same cluster size as the verified 8-phase template.
// z==2 (V): the 256x128 tile is one head x 256 s-rows; epilogue restages it
// as Cs[256][130] (stride 65 dwords, %32==1 -> conflict-free column reads)
// aliased on the A-buffers and computes the db4 DWT in-block: cA -> out2,
// cD^T (+ones row 67, zero rows 68..79) -> cdt.
__global__ __launch_bounds__(512) void qkv_gemm(
    const short* __restrict__ xb, const short* __restrict__ Wb,
    short* __restrict__ Qb, short* __restrict__ Kb,
    float* __restrict__ outA, short* __restrict__ cdt)
{
    __shared__ __align__(16) short Asb[3][256 * 64];   // 3 x 32KB
    __shared__ __align__(16) short Bsb[3][128 * 64];   // 3 x 16KB  (144KB total)
    const int tid  = threadIdx.x;
    const int wid  = tid >> 6;
    const int lane = tid & 63;
    const int l15  = lane & 15;
    const int quad = lane >> 4;
    const int rx   = l15 & 7;
    const int wm   = wid >> 1;            // 0..3  (m-position of wave)
    const int wn   = wid & 1;             // 0..1  (n-position of wave)
    const int m0 = blockIdx.x * 256;
    const int by = blockIdx.y;            // 0..23
    const int z  = by >> 3;               // 0=Q 1=K 2=V
    const int n0 = (by & 7) * 128;        // n-offset within the z-th weight
    const short* W = Wb + (size_t)z * HD * HD;
    // q scale folded with log2(e) so attention softmax can use exp2
    const float scale = (z == 0) ? 0.12751743786072596f : 1.0f;
    const int srow = lane >> 3;                 // staging: 8 lanes per 128B row
    const int sch  = (lane & 7) ^ srow;         // XOR-swizzled source chunk

    floatx4 acc[4][4] = {};

    // stage A tile (256x64, 32 issues -> 4/wave) / B tile (128x64 -> 2/wave)
    auto stA = [&](int bf, int t) {
        #pragma unroll
        for (int i = 0; i < 4; ++i) {
            int ti = wid * 4 + i;
            glds16(&Asb[bf][ti * 512],
                   xb + (size_t)(m0 + ti * 8 + srow) * HD + t * 64 + sch * 8);
        }
    };
    auto stB = [&](int bf, int t) {
        #pragma unroll
        for (int i = 0; i < 2; ++i) {
            int ti = wid * 2 + i;
            glds16(&Bsb[bf][ti * 512],
                   W + (size_t)(n0 + ti * 8 + srow) * HD + t * 64 + sch * 8);
        }
    };

#define VM6 asm volatile("s_waitcnt vmcnt(6)" ::: "memory")
#define VM0 asm volatile("s_waitcnt vmcnt(0)" ::: "memory")
#define BARRIER do { asm volatile("" ::: "memory"); \
                     __builtin_amdgcn_s_barrier(); \
                     asm volatile("" ::: "memory"); } while (0)

    // prologue: tiles 0,1 -> bufs 0,1; wait tile0 complete (leave tile1's 6)
    stA(0, 0); stB(0, 0);
    stA(1, 1); stB(1, 1);
    VM6; BARRIER;

    #pragma unroll
    for (int t = 0; t < 16; ++t) {
        const int cur = t % 3;
        const int sb  = (t + 2) % 3;
        // ---- phase 0: ks=0 ----
        {
            short8 af[4], bf4[4];
            #pragma unroll
            for (int mt = 0; mt < 4; ++mt)
                af[mt] = *(const short8*)
                    &Asb[cur][(wm * 64 + mt * 16 + l15) * 64 + ((quad ^ rx) * 8)];
            #pragma unroll
            for (int nt = 0; nt < 4; ++nt)
                bf4[nt] = *(const short8*)
                    &Bsb[cur][(wn * 64 + nt * 16 + l15) * 64 + ((quad ^ rx) * 8)];
            if (t < 14) stA(sb, t + 2);
            BARRIER;
            __builtin_amdgcn_s_setprio(1);
            #pragma unroll
            for (int mt = 0; mt < 4; ++mt)
                #pragma unroll
                for (int nt = 0; nt < 4; ++nt)
                    acc[mt][nt] = __builtin_amdgcn_mfma_f32_16x16x32_bf16(
                        af[mt], bf4[nt], acc[mt][nt], 0, 0, 0);
            __builtin_amdgcn_s_setprio(0);
            BARRIER;
        }
        // ---- phase 1: ks=1 ----
        {
            short8 af[4], bf4[4];
            #pragma unroll
            for (int mt = 0; mt < 4; ++mt)
                af[mt] = *(const short8*)
                    &Asb[cur][(wm * 64 + mt * 16 + l15) * 64 + (((4 + quad) ^ rx) * 8)];
            #pragma unroll
            for (int nt = 0; nt < 4; ++nt)
                bf4[nt] = *(const short8*)
                    &Bsb[cur][(wn * 64 + nt * 16 + l15) * 64 + (((4 + quad) ^ rx) * 8)];
            if (t < 14) stB(sb, t + 2);
            if (t < 14) { VM6; } else if (t == 14) { VM0; }
            BARRIER;
            __builtin_amdgcn_s_setprio(1);
            #pragma unroll
            for (int mt = 0; mt < 4; ++mt)
                #pragma unroll
                for (int nt = 0; nt < 4; ++nt)
                    acc[mt][nt] = __builtin_amdgcn_mfma_f32_16x16x32_bf16(
                        af[mt], bf4[nt], acc[mt][nt], 0, 0, 0);
            __builtin_amdgcn_s_setprio(0);
            BARRIER;
        }
    }
    __syncthreads();     // drain everything before LDS reuse / return

    // C layout per fragment: col = l15 (N), row = quad*4+reg (M).
    if (z != 2) {
        short* Yb = (z == 0) ? Qb : Kb;
        #pragma unroll
        for (int mt = 0; mt < 4; ++mt)
            #pragma unroll
            for (int nt = 0; nt < 4; ++nt)
                #pragma unroll
                for (int reg = 0; reg < 4; ++reg) {
                    int rg = m0 + wm * 64 + mt * 16 + quad * 4 + reg;
                    int cg = n0 + wn * 64 + nt * 16 + l15;
                    int b = rg >> 11, s = rg & 2047;
                    int h = cg >> 7,  d = cg & 127;
                    Yb[((size_t)(b * NH + h) * S_ + s) * DK + d] =
                        f2bf(acc[mt][nt][reg] * scale);
                }
        return;
    }
    // ---- z==2: V tile (1 head x 256 s-rows) -> LDS, fused db4 DWT ----
    short* Cs = &Asb[0][0];              // 256 x 130 shorts = 66.5KB (in Asb's 96KB)
    #pragma unroll
    for (int mt = 0; mt < 4; ++mt)
        #pragma unroll
        for (int nt = 0; nt < 4; ++nt)
            #pragma unroll
            for (int reg = 0; reg < 4; ++reg) {
                int r = wm * 64 + mt * 16 + quad * 4 + reg;
                int c = wn * 64 + nt * 16 + l15;
                Cs[r * 130 + c] = f2bf(acc[mt][nt][reg]);
            }
    __syncthreads();
    const int rl    = tid & 255;                 // local V row (s)
    const int chunk = tid >> 8;                  // t-half 0/1
    const int rg = m0 + rl;
    const int b = rg >> 11, s = rg & 2047;
    const int bh = b * NH + (by & 7);            // h == by&7
    const short* vr = Cs + rl * 130;
    auto getv = [&](int i) -> float {
        int k = (i < 6) ? (5 - i) : (i < 134) ? (i - 6) : (261 - i);
        return bf2f(vr[k]);
    };
    const int t0 = chunk * 34;
    const int t1 = (chunk == 0) ? 34 : WA;
    float win[8];
    #pragma unroll
    for (int j = 0; j < 8; ++j) win[j] = getv(2 * t0 + j);
    float* oA = outA + ((size_t)bh * S_ + s) * WA;
    for (int t = t0; t < t1; ++t) {
        float lo = 0.f, hi = 0.f;
        #pragma unroll
        for (int j = 0; j < 8; ++j) { lo += win[j] * FLO[j]; hi += win[j] * FHI[j]; }
        oA[t] = lo;                                          // contiguous per thread
        cdt[((size_t)bh * WPAD + t) * S_ + s] = f2bf(hi);    // lane-coalesced over s
        #pragma unroll
        for (int j = 0; j < 6; ++j) win[j] = win[j + 2];
        if (t + 1 < t1) { win[6] = getv(2 * t + 8); win[7] = getv(2 * t + 9); }
    }
    if (chunk == 1) {
        #pragma unroll
        for (int w = WA; w < WPAD; ++w)
            cdt[((size_t)bh * WPAD + w) * S_ + s] =
                (w == 67) ? (short)0x3F80 : (short)0;   // ones row 67 (l), else 0
    }
#undef BARRIER
#undef VM6
#undef VM0
}

// ---------------- flash attention: out1 = softmax(QK^T) @ cD ----------------
// 128 q-rows/block (32/wave), grid 16x32=512. Single-buffer staging (proven
// vs dbuf/split-K). S^T trick (A=K, B=Q) packs P as b64 into wave-private
// XOR-swizzled LDS. Unnormalized softmax (|s| < ~15, exp2 domain); the l-sum
// comes FREE from the PV MFMA via the ones-row at w=67 (col 67 of j=4 tile).
__global__ __launch_bounds__(256, 2) void attn_kernel(
    const short* __restrict__ Qb, const short* __restrict__ Kb,
    const short* __restrict__ cdt, float* __restrict__ out1)
{
    __shared__ __align__(16) short Ks[64 * 128];      // 16KB, 16 chunks/row
    __shared__ __align__(16) short Ds[WPAD * 64];     // 10KB, 8 chunks/row
    __shared__ __align__(16) short Pt[8 * 1024];      // 16KB, wave-private P
    const int tid  = threadIdx.x;
    const int wv   = tid >> 6;
    const int lane = tid & 63;
    const int l15  = lane & 15;
    const int quad = lane >> 4;
    const int qt = blockIdx.x;           // 0..15 (128 q-rows each)
    const int bh = blockIdx.y;           // 0..31
    const int b = bh >> 3, h = bh & 7;
    const int rxor = l15 & 7;

    // Q fragments from global, once. Lane layout = row l15, k = quad*8+j
    // (identical for A- and B-operands, so they serve as B in S^T = K Q^T).
    short8 aq[2][4];
    #pragma unroll
    for (int n = 0; n < 2; ++n) {
        const short* qrow =
            Qb + ((size_t)bh * S_ + qt * 128 + wv * 32 + n * 16 + l15) * DK;
        #pragma unroll
        for (int s4 = 0; s4 < 4; ++s4)
            aq[n][s4] = *(const short8*)(qrow + s4 * 32 + quad * 8);
    }

    floatx4 O[2][5] = {};                // j=4 tile col 67 accumulates l

    const short* kbase = Kb + (size_t)bh * S_ * DK;
    const int krow = lane >> 4;                    // K staging: 4 rows/issue
    const int kch  = (lane & 15);
    const int drow = lane >> 3;                    // D staging: 8 rows/issue
    const int dch  = (lane & 7) ^ (drow & 7);
    short* ptw = Pt + wv * 2048;                   // this wave's P (2 tiles)

    for (int kt = 0; kt < 32; ++kt) {
        __syncthreads();                 // prior iter done reading Ks/Ds
        #pragma unroll
        for (int i = 0; i < 4; ++i) {    // K tile: 64 rows x 256B, 16 issues
            int ti = wv * 4 + i;
            int r  = ti * 4 + krow;
            int ch = kch ^ (r & 7);
            glds16(Ks + ti * 512, kbase + ((size_t)kt * 64 + r) * DK + ch * 8);
        }
        #pragma unroll
        for (int i = 0; i < 3; ++i) {    // D tile: 80 rows x 128B, 10 issues
            int t = wv + i * 4;
            if (t < 10) {
                int r = t * 8 + drow;
                glds16(Ds + t * 512,
                       cdt + ((size_t)bh * WPAD + r) * S_ + kt * 64 + dch * 8);
            }
        }
        __syncthreads();                 // vmcnt drained -> tiles ready

        // S^T = K Q^T : C col=l15=q-row, row=quad*4+reg=key
        floatx4 sc[2][4] = {};
        #pragma unroll
        for (int s4 = 0; s4 < 4; ++s4) {
            short8 kf[4];
            #pragma unroll
            for (int mt = 0; mt < 4; ++mt) {
                int ch = (s4 * 4 + quad) ^ rxor;
                kf[mt] = *(const short8*)&Ks[(mt * 16 + l15) * 128 + ch * 8];
            }
            #pragma unroll
            for (int n = 0; n < 2; ++n)
                #pragma unroll
                for (int mt = 0; mt < 4; ++mt)
                    sc[n][mt] = __builtin_amdgcn_mfma_f32_16x16x32_bf16(
                        kf[mt], aq[n][s4], sc[n][mt], 0, 0, 0);
        }
        // p = 2^s; 4 regs = 4 consecutive keys of q-row n*16+l15 -> b64 pack
        #pragma unroll
        for (int n = 0; n < 2; ++n) {
            #pragma unroll
            for (int mt = 0; mt < 4; ++mt) {
                short4v pk;
                #pragma unroll
                for (int reg = 0; reg < 4; ++reg)
                    pk[reg] = f2bf_trunc(hexp2(sc[n][mt][reg]));
                int ch = (mt * 2 + (quad >> 1)) ^ rxor;
                *(short4v*)&ptw[n * 1024 + l15 * 64 + ch * 8 + (quad & 1) * 4] = pk;
            }
        }
        // O += P @ cD   (col 67 of j=4 accumulates l via the ones row)
        short8 ap[2][2];
        #pragma unroll
        for (int mt = 0; mt < 2; ++mt)
            #pragma unroll
            for (int ks = 0; ks < 2; ++ks) {
                int ch = (ks * 4 + quad) ^ rxor;
                ap[mt][ks] = *(const short8*)&ptw[mt * 1024 + l15 * 64 + ch * 8];
            }
        #pragma unroll
        for (int j = 0; j < 5; ++j) {
            #pragma unroll
            for (int ks = 0; ks < 2; ++ks) {
                int ch = (ks * 4 + quad) ^ rxor;
                short8 bd = *(const short8*)&Ds[(j * 16 + l15) * 64 + ch * 8];
                #pragma unroll
                for (int mt = 0; mt < 2; ++mt)
                    O[mt][j] = __builtin_amdgcn_mfma_f32_16x16x32_bf16(
                        ap[mt][ks], bd, O[mt][j], 0, 0, 0);
            }
        }
    }
    // l(r) sits at element (row r, col 67) = lane (r>>2)*16+3, reg r&3 of j=4.
    float rl[2][4];
    #pragma unroll
    for (int mt = 0; mt < 2; ++mt)
        #pragma unroll
        for (int reg = 0; reg < 4; ++reg)
            rl[mt][reg] = 1.0f / __shfl(O[mt][4][reg], (quad << 4) | 3, 64);
    // epilogue: out1[b][q][h*67+w] = O * (1/l)   (w >= 67 dropped)
    #pragma unroll
    for (int mt = 0; mt < 2; ++mt)
        #pragma unroll
        for (int j = 0; j < 5; ++j) {
            int w = j * 16 + l15;
            if (w < WA) {
                #pragma unroll
                for (int reg = 0; reg < 4; ++reg) {
                    int qrow_g = qt * 128 + wv * 32 + mt * 16 + quad * 4 + reg;
                    out1[((size_t)(b * S_ + qrow_g)) * (NH * WA) + h * WA + w] =
                        O[mt][j][reg] * rl[mt][reg];
                }
            }
        }
}

extern "C" void kernel_launch(void* const* d_in, const int* in_sizes, int n_in,
                              void* d_out, int out_size, void* d_ws, size_t ws_size,
                              hipStream_t stream)
{
    const float* x  = (const float*)d_in[0];
    const float* Wq = (const float*)d_in[1];
    const float* Wk = (const float*)d_in[2];
    const float* Wv = (const float*)d_in[3];
    float* out = (float*)d_out;

    const size_t x_elems   = (size_t)B_ * S_ * HD;           // 8,388,608
    const size_t w_elems   = (size_t)HD * HD;                // 1,048,576
    const size_t qkv_elems = (size_t)B_ * NH * S_ * DK;      // 8,388,608
    short* xb  = (short*)d_ws;
    short* Wb  = xb + x_elems;                               // 3 concatenated
    short* Qb  = Wb + 3 * w_elems;
    short* Kb  = Qb + qkv_elems;
    short* cdt = Kb + qkv_elems;                             // (b,h,w=80,s) bf16
    float* out1 = out;                                       // (B,S,536)
    float* out2 = out + (size_t)B_ * S_ * NH * WA;           // (B,H,S,67)

    cvt_all<<<dim3(5632), 256, 0, stream>>>(x, Wq, Wk, Wv, xb, Wb);
    qkv_gemm<<<dim3(32, 24), 512, 0, stream>>>(xb, Wb, Qb, Kb, out2, cdt);
    attn_kernel<<<dim3(16, 32), 256, 0, stream>>>(Qb, Kb, cdt, out1);
}

// Round 3
// 222.250 us; speedup vs baseline: 1.0890x; 1.0518x over previous
//
#include <hip/hip_runtime.h>
#include <hip/hip_bf16.h>

#define B_ 4
#define S_ 2048
#define HD 1024
#define NH 8
#define DK 128
#define WA 67
#define WPAD 80      // cD^T rows: 0..66 data, 67 = ones (l-column), 68..79 zero

typedef __attribute__((ext_vector_type(8))) short short8;
typedef __attribute__((ext_vector_type(4))) short short4v;
typedef __attribute__((ext_vector_type(4))) float floatx4;

// hardware exp2: one v_exp_f32 (avoid __exp2f - glibc macro collision)
__device__ __forceinline__ float hexp2(float x) { return __builtin_amdgcn_exp2f(x); }

__device__ __forceinline__ short f2bf(float f) {
    union { float f; unsigned u; } c; c.f = f;
    unsigned u = c.u;
    u += 0x7FFF + ((u >> 16) & 1);          // RTNE
    return (short)(u >> 16);
}
__device__ __forceinline__ float bf2f(short s) {
    union { unsigned u; float f; } c; c.u = ((unsigned)(unsigned short)s) << 16;
    return c.f;
}
__device__ __forceinline__ short f2bf_trunc(float f) {
    union { float f; unsigned u; } c; c.f = f;
    return (short)(c.u >> 16);
}

// async 16B global->LDS DMA; LDS dest = wave-uniform base, lane i lands at
// base + i*16. Per-lane global address is free to choose -> XOR swizzle there.
__device__ __forceinline__ void glds16(void* lds, const void* g) {
    __builtin_amdgcn_global_load_lds(
        (const __attribute__((address_space(1))) unsigned*)g,
        (__attribute__((address_space(3))) unsigned*)lds, 16, 0, 0);
}

// db4 filters, pre-reversed for correlation: F[j] = DEC_*[7-j]
__device__ __constant__ float FLO[8] = {
    0.23037781330885523f,  0.7148465705525415f,  0.6308807679295904f,
   -0.02798376941698385f, -0.18703481171888114f, 0.030841381835986965f,
    0.032883011666982945f, -0.010597401784997278f };
__device__ __constant__ float FHI[8] = {
   -0.010597401784997278f, -0.032883011666982945f, 0.030841381835986965f,
    0.18703481171888114f,  -0.02798376941698385f, -0.6308807679295904f,
    0.7148465705525415f,   -0.23037781330885523f };

// ------- fp32 -> bf16 bulk convert, all four inputs in ONE launch ----------
__global__ __launch_bounds__(256) void cvt_all(
    const float* __restrict__ x,  const float* __restrict__ wq,
    const float* __restrict__ wk, const float* __restrict__ wv,
    short* __restrict__ xb, short* __restrict__ wb)
{
    const size_t w_elems = (size_t)HD * HD;
    int blk = blockIdx.x;
    const float* src; short* dst; int lb;
    if (blk < 4096)      { src = x;  dst = xb;               lb = blk; }
    else if (blk < 4608) { src = wq; dst = wb;               lb = blk - 4096; }
    else if (blk < 5120) { src = wk; dst = wb + w_elems;     lb = blk - 4608; }
    else                 { src = wv; dst = wb + 2 * w_elems; lb = blk - 5120; }
    int i = lb * 256 + threadIdx.x;
    const float4* s = (const float4*)src + (size_t)i * 2;
    float4 f0 = s[0], f1 = s[1];
    short8 o;
    o[0] = f2bf(f0.x); o[1] = f2bf(f0.y); o[2] = f2bf(f0.z); o[3] = f2bf(f0.w);
    o[4] = f2bf(f1.x); o[5] = f2bf(f1.y); o[6] = f2bf(f1.z); o[7] = f2bf(f1.w);
    *((short8*)dst + i) = o;
}

// ------- QKV projection + fused DWT: 128x128xBK64, dbuf, 2 blocks/CU -------
// One fused GEMM over N=3072 (Wq|Wk|Wv). Tile 128(M)x128(N), BK=64, 4 waves
// (2x2, wave tile 64x64). 64KB LDS double-buffer -> 2 blocks/CU (16 waves/CU):
// cross-block TLP hides the per-tile drain (the m114 overlap round-1/2 sold
// off by running 1 block/CU in lockstep). Grid 64x24 = 1536 blocks = 3 clean
// co-residency rounds of 512. Per K-tile (T3-minimal recipe): stage tile t+1
// FIRST (8 glds into buf nxt), then 2x {8 ds_read_b128, setprio(1), 16 MFMA,
// setprio(0)} on buf cur, then ONE vmcnt(0)+barrier at the tile boundary --
// the drain has a full tile (~700cy) of issue-to-wait cover, so it completes
// in ~0 cy; residue is covered by the co-resident block.
// z==2 (V): tile = one head x 128 s-rows; epilogue restages it as
// Cs[128][130] (stride 65 dwords, odd -> conflict-free column reads) aliased
// on the LDS pool and computes the db4 DWT in-block: cA -> out2, cD^T
// (+ones row 67, zero rows 68..79) -> cdt.
__global__ __launch_bounds__(256, 2) void qkv_gemm(
    const short* __restrict__ xb, const short* __restrict__ Wb,
    short* __restrict__ Qb, short* __restrict__ Kb,
    float* __restrict__ outA, short* __restrict__ cdt)
{
    __shared__ __align__(16) short SM[32768];   // 64KB: [A0|A1|B0|B1] 16KB each
    const int tid  = threadIdx.x;
    const int wid  = tid >> 6;            // 0..3
    const int lane = tid & 63;
    const int l15  = lane & 15;
    const int quad = lane >> 4;
    const int rx   = l15 & 7;
    const int wm   = wid >> 1;            // 0..1  (m-position of wave)
    const int wn   = wid & 1;             // 0..1  (n-position of wave)
    const int m0 = blockIdx.x * 128;
    const int by = blockIdx.y;            // 0..23
    const int z  = by >> 3;               // 0=Q 1=K 2=V
    const int n0 = (by & 7) * 128;        // n-offset within the z-th weight
    const short* W = Wb + (size_t)z * HD * HD;
    // q scale folded with log2(e) so attention softmax can use exp2
    const float scale = (z == 0) ? 0.12751743786072596f : 1.0f;
    const int srow = lane >> 3;                 // staging: 8 lanes per 128B row
    const int sch  = (lane & 7) ^ srow;         // XOR-swizzled source chunk

    floatx4 acc[4][4] = {};

    auto Abuf = [&](int bf) -> short* { return SM + bf * 8192; };
    auto Bbuf = [&](int bf) -> short* { return SM + 16384 + bf * 8192; };

    // stage one 128x64 tile half: 16 x 1KB issues -> 4 per wave
    auto stA = [&](int bf, int t) {
        short* d = Abuf(bf);
        #pragma unroll
        for (int i = 0; i < 4; ++i) {
            int ti = wid * 4 + i;
            glds16(d + ti * 512,
                   xb + (size_t)(m0 + ti * 8 + srow) * HD + t * 64 + sch * 8);
        }
    };
    auto stB = [&](int bf, int t) {
        short* d = Bbuf(bf);
        #pragma unroll
        for (int i = 0; i < 4; ++i) {
            int ti = wid * 4 + i;
            glds16(d + ti * 512,
                   W + (size_t)(n0 + ti * 8 + srow) * HD + t * 64 + sch * 8);
        }
    };

#define VM0 asm volatile("s_waitcnt vmcnt(0)" ::: "memory")
#define BARRIER do { asm volatile("" ::: "memory"); \
                     __builtin_amdgcn_s_barrier(); \
                     asm volatile("" ::: "memory"); } while (0)

    // prologue: tile 0 -> buf 0, full drain once
    stA(0, 0); stB(0, 0);
    VM0; BARRIER;

    for (int t = 0; t < 16; ++t) {
        const int cur = t & 1, nxt = cur ^ 1;
        if (t < 15) { stA(nxt, t + 1); stB(nxt, t + 1); }   // issue-early
        const short* Ab = Abuf(cur);
        const short* Bb = Bbuf(cur);
        #pragma unroll
        for (int ks = 0; ks < 2; ++ks) {
            short8 af[4], bf4[4];
            #pragma unroll
            for (int mt = 0; mt < 4; ++mt)
                af[mt] = *(const short8*)
                    &Ab[(wm * 64 + mt * 16 + l15) * 64 + (((ks * 4 + quad) ^ rx) * 8)];
            #pragma unroll
            for (int nt = 0; nt < 4; ++nt)
                bf4[nt] = *(const short8*)
                    &Bb[(wn * 64 + nt * 16 + l15) * 64 + (((ks * 4 + quad) ^ rx) * 8)];
            __builtin_amdgcn_s_setprio(1);
            #pragma unroll
            for (int mt = 0; mt < 4; ++mt)
                #pragma unroll
                for (int nt = 0; nt < 4; ++nt)
                    acc[mt][nt] = __builtin_amdgcn_mfma_f32_16x16x32_bf16(
                        af[mt], bf4[nt], acc[mt][nt], 0, 0, 0);
            __builtin_amdgcn_s_setprio(0);
        }
        VM0;           // tile t+1's 8 loads: issued a full tile ago -> ~0 wait
        BARRIER;       // buf[nxt] visible to all; all waves done with buf[cur]
    }

    // C layout per fragment: col = l15 (N), row = quad*4+reg (M).
    if (z != 2) {
        short* Yb = (z == 0) ? Qb : Kb;
        #pragma unroll
        for (int mt = 0; mt < 4; ++mt)
            #pragma unroll
            for (int nt = 0; nt < 4; ++nt)
                #pragma unroll
                for (int reg = 0; reg < 4; ++reg) {
                    int rg = m0 + wm * 64 + mt * 16 + quad * 4 + reg;
                    int cg = n0 + wn * 64 + nt * 16 + l15;
                    int b = rg >> 11, s = rg & 2047;
                    int h = cg >> 7,  d = cg & 127;
                    Yb[((size_t)(b * NH + h) * S_ + s) * DK + d] =
                        f2bf(acc[mt][nt][reg] * scale);
                }
        return;
    }
    // ---- z==2: V tile (1 head x 128 s-rows) -> LDS, fused db4 DWT ----
    short* Cs = SM;                      // 128 x 130 shorts = 33.3KB (in 64KB)
    #pragma unroll
    for (int mt = 0; mt < 4; ++mt)
        #pragma unroll
        for (int nt = 0; nt < 4; ++nt)
            #pragma unroll
            for (int reg = 0; reg < 4; ++reg) {
                int r = wm * 64 + mt * 16 + quad * 4 + reg;
                int c = wn * 64 + nt * 16 + l15;
                Cs[r * 130 + c] = f2bf(acc[mt][nt][reg]);
            }
    __syncthreads();
    const int rl    = tid & 127;                 // local V row (s)
    const int chunk = tid >> 7;                  // t-half 0/1
    const int rg = m0 + rl;
    const int b = rg >> 11, s = rg & 2047;
    const int bh = b * NH + (by & 7);            // h == by&7
    const short* vr = Cs + rl * 130;
    auto getv = [&](int i) -> float {
        int k = (i < 6) ? (5 - i) : (i < 134) ? (i - 6) : (261 - i);
        return bf2f(vr[k]);
    };
    const int t0 = chunk * 34;
    const int t1 = (chunk == 0) ? 34 : WA;
    float win[8];
    #pragma unroll
    for (int j = 0; j < 8; ++j) win[j] = getv(2 * t0 + j);
    float* oA = outA + ((size_t)bh * S_ + s) * WA;
    for (int t = t0; t < t1; ++t) {
        float lo = 0.f, hi = 0.f;
        #pragma unroll
        for (int j = 0; j < 8; ++j) { lo += win[j] * FLO[j]; hi += win[j] * FHI[j]; }
        oA[t] = lo;                                          // contiguous per thread
        cdt[((size_t)bh * WPAD + t) * S_ + s] = f2bf(hi);    // lane-coalesced over s
        #pragma unroll
        for (int j = 0; j < 6; ++j) win[j] = win[j + 2];
        if (t + 1 < t1) { win[6] = getv(2 * t + 8); win[7] = getv(2 * t + 9); }
    }
    if (chunk == 1) {
        #pragma unroll
        for (int w = WA; w < WPAD; ++w)
            cdt[((size_t)bh * WPAD + w) * S_ + s] =
                (w == 67) ? (short)0x3F80 : (short)0;   // ones row 67 (l), else 0
    }
#undef BARRIER
#undef VM0
}

// ---------------- flash attention: out1 = softmax(QK^T) @ cD ----------------
// 128 q-rows/block (32/wave), grid 16x32=512. Single-buffer staging (proven
// vs dbuf/split-K). S^T trick (A=K, B=Q) packs P as b64 into wave-private
// XOR-swizzled LDS. Unnormalized softmax (|s| < ~15, exp2 domain); the l-sum
// comes FREE from the PV MFMA via the ones-row at w=67 (col 67 of j=4 tile).
__global__ __launch_bounds__(256, 2) void attn_kernel(
    const short* __restrict__ Qb, const short* __restrict__ Kb,
    const short* __restrict__ cdt, float* __restrict__ out1)
{
    __shared__ __align__(16) short Ks[64 * 128];      // 16KB, 16 chunks/row
    __shared__ __align__(16) short Ds[WPAD * 64];     // 10KB, 8 chunks/row
    __shared__ __align__(16) short Pt[8 * 1024];      // 16KB, wave-private P
    const int tid  = threadIdx.x;
    const int wv   = tid >> 6;
    const int lane = tid & 63;
    const int l15  = lane & 15;
    const int quad = lane >> 4;
    const int qt = blockIdx.x;           // 0..15 (128 q-rows each)
    const int bh = blockIdx.y;           // 0..31
    const int b = bh >> 3, h = bh & 7;
    const int rxor = l15 & 7;

    // Q fragments from global, once. Lane layout = row l15, k = quad*8+j
    // (identical for A- and B-operands, so they serve as B in S^T = K Q^T).
    short8 aq[2][4];
    #pragma unroll
    for (int n = 0; n < 2; ++n) {
        const short* qrow =
            Qb + ((size_t)bh * S_ + qt * 128 + wv * 32 + n * 16 + l15) * DK;
        #pragma unroll
        for (int s4 = 0; s4 < 4; ++s4)
            aq[n][s4] = *(const short8*)(qrow + s4 * 32 + quad * 8);
    }

    floatx4 O[2][5] = {};                // j=4 tile col 67 accumulates l

    const short* kbase = Kb + (size_t)bh * S_ * DK;
    const int krow = lane >> 4;                    // K staging: 4 rows/issue
    const int kch  = (lane & 15);
    const int drow = lane >> 3;                    // D staging: 8 rows/issue
    const int dch  = (lane & 7) ^ (drow & 7);
    short* ptw = Pt + wv * 2048;                   // this wave's P (2 tiles)

    for (int kt = 0; kt < 32; ++kt) {
        __syncthreads();                 // prior iter done reading Ks/Ds
        #pragma unroll
        for (int i = 0; i < 4; ++i) {    // K tile: 64 rows x 256B, 16 issues
            int ti = wv * 4 + i;
            int r  = ti * 4 + krow;
            int ch = kch ^ (r & 7);
            glds16(Ks + ti * 512, kbase + ((size_t)kt * 64 + r) * DK + ch * 8);
        }
        #pragma unroll
        for (int i = 0; i < 3; ++i) {    // D tile: 80 rows x 128B, 10 issues
            int t = wv + i * 4;
            if (t < 10) {
                int r = t * 8 + drow;
                glds16(Ds + t * 512,
                       cdt + ((size_t)bh * WPAD + r) * S_ + kt * 64 + dch * 8);
            }
        }
        __syncthreads();                 // vmcnt drained -> tiles ready

        // S^T = K Q^T : C col=l15=q-row, row=quad*4+reg=key
        floatx4 sc[2][4] = {};
        #pragma unroll
        for (int s4 = 0; s4 < 4; ++s4) {
            short8 kf[4];
            #pragma unroll
            for (int mt = 0; mt < 4; ++mt) {
                int ch = (s4 * 4 + quad) ^ rxor;
                kf[mt] = *(const short8*)&Ks[(mt * 16 + l15) * 128 + ch * 8];
            }
            #pragma unroll
            for (int n = 0; n < 2; ++n)
                #pragma unroll
                for (int mt = 0; mt < 4; ++mt)
                    sc[n][mt] = __builtin_amdgcn_mfma_f32_16x16x32_bf16(
                        kf[mt], aq[n][s4], sc[n][mt], 0, 0, 0);
        }
        // p = 2^s; 4 regs = 4 consecutive keys of q-row n*16+l15 -> b64 pack
        #pragma unroll
        for (int n = 0; n < 2; ++n) {
            #pragma unroll
            for (int mt = 0; mt < 4; ++mt) {
                short4v pk;
                #pragma unroll
                for (int reg = 0; reg < 4; ++reg)
                    pk[reg] = f2bf_trunc(hexp2(sc[n][mt][reg]));
                int ch = (mt * 2 + (quad >> 1)) ^ rxor;
                *(short4v*)&ptw[n * 1024 + l15 * 64 + ch * 8 + (quad & 1) * 4] = pk;
            }
        }
        // O += P @ cD   (col 67 of j=4 accumulates l via the ones row)
        short8 ap[2][2];
        #pragma unroll
        for (int mt = 0; mt < 2; ++mt)
            #pragma unroll
            for (int ks = 0; ks < 2; ++ks) {
                int ch = (ks * 4 + quad) ^ rxor;
                ap[mt][ks] = *(const short8*)&ptw[mt * 1024 + l15 * 64 + ch * 8];
            }
        #pragma unroll
        for (int j = 0; j < 5; ++j) {
            #pragma unroll
            for (int ks = 0; ks < 2; ++ks) {
                int ch = (ks * 4 + quad) ^ rxor;
                short8 bd = *(const short8*)&Ds[(j * 16 + l15) * 64 + ch * 8];
                #pragma unroll
                for (int mt = 0; mt < 2; ++mt)
                    O[mt][j] = __builtin_amdgcn_mfma_f32_16x16x32_bf16(
                        ap[mt][ks], bd, O[mt][j], 0, 0, 0);
            }
        }
    }
    // l(r) sits at element (row r, col 67) = lane (r>>2)*16+3, reg r&3 of j=4.
    float rl[2][4];
    #pragma unroll
    for (int mt = 0; mt < 2; ++mt)
        #pragma unroll
        for (int reg = 0; reg < 4; ++reg)
            rl[mt][reg] = 1.0f / __shfl(O[mt][4][reg], (quad << 4) | 3, 64);
    // epilogue: out1[b][q][h*67+w] = O * (1/l)   (w >= 67 dropped)
    #pragma unroll
    for (int mt = 0; mt < 2; ++mt)
        #pragma unroll
        for (int j = 0; j < 5; ++j) {
            int w = j * 16 + l15;
            if (w < WA) {
                #pragma unroll
                for (int reg = 0; reg < 4; ++reg) {
                    int qrow_g = qt * 128 + wv * 32 + mt * 16 + quad * 4 + reg;
                    out1[((size_t)(b * S_ + qrow_g)) * (NH * WA) + h * WA + w] =
                        O[mt][j][reg] * rl[mt][reg];
                }
            }
        }
}

extern "C" void kernel_launch(void* const* d_in, const int* in_sizes, int n_in,
                              void* d_out, int out_size, void* d_ws, size_t ws_size,
                              hipStream_t stream)
{
    const float* x  = (const float*)d_in[0];
    const float* Wq = (const float*)d_in[1];
    const float* Wk = (const float*)d_in[2];
    const float* Wv = (const float*)d_in[3];
    float* out = (float*)d_out;

    const size_t x_elems   = (size_t)B_ * S_ * HD;           // 8,388,608
    const size_t w_elems   = (size_t)HD * HD;                // 1,048,576
    const size_t qkv_elems = (size_t)B_ * NH * S_ * DK;      // 8,388,608
    short* xb  = (short*)d_ws;
    short* Wb  = xb + x_elems;                               // 3 concatenated
    short* Qb  = Wb + 3 * w_elems;
    short* Kb  = Qb + qkv_elems;
    short* cdt = Kb + qkv_elems;                             // (b,h,w=80,s) bf16
    float* out1 = out;                                       // (B,S,536)
    float* out2 = out + (size_t)B_ * S_ * NH * WA;           // (B,H,S,67)

    cvt_all<<<dim3(5632), 256, 0, stream>>>(x, Wq, Wk, Wv, xb, Wb);
    qkv_gemm<<<dim3(64, 24), 256, 0, stream>>>(xb, Wb, Qb, Kb, out2, cdt);
    attn_kernel<<<dim3(16, 32), 256, 0, stream>>>(Qb, Kb, cdt, out1);
}